// Round 1
// baseline (4977.114 us; speedup 1.0000x reference)
//
#include <hip/hip_runtime.h>
#include <math.h>

#define NT     365
#define NGRID  3000
#define NX     20
#define H      256
#define CPB    15
#define NBLK   (NGRID/CPB)     // 200 blocks, 1 per CU
#define THREADS 1024           // 16 waves, 4 per SIMD

// packed weight sizes (ushorts)
// wpk HI-ONLY: [g 16][kap 16][q 4][lane 64][e 8]
#define WPK_US   (16*16*4*64*8)   // 524,288
#define WPKIN_US (16*2*64*8)      // 16,384

#define KPERS 3       // kaps 8..10 persisted in VGPRs (48 VGPRs/wave)
#define KPRE  11      // kap 11 prefetched across the step boundary

typedef short v8s __attribute__((ext_vector_type(8)));
typedef float v4f __attribute__((ext_vector_type(4)));
#define MFMA_BF16 __builtin_amdgcn_mfma_f32_16x16x32_bf16

__device__ __forceinline__ unsigned short f2bf(float f) {
    unsigned int u = __float_as_uint(f);
    u += 0x7fffu + ((u >> 16) & 1u);          // RTNE
    return (unsigned short)(u >> 16);
}
__device__ __forceinline__ float bf2f(unsigned short h) {
    return __uint_as_float(((unsigned int)h) << 16);
}
__device__ __forceinline__ float sigm(float x)  { return 1.0f / (1.0f + __expf(-x)); }
__device__ __forceinline__ float tanh_f(float x){ return 2.0f * sigm(2.0f * x) - 1.0f; }

// ---------------- weight pre-pack (unchanged) ----------------
__global__ void prep_kernel(const float* __restrict__ w_in,
                            const float* __restrict__ w_ih,
                            const float* __restrict__ w_hh,
                            const float* __restrict__ b_ih,
                            const float* __restrict__ b_hh,
                            unsigned short* __restrict__ wpk,
                            unsigned short* __restrict__ wpkin,
                            float* __restrict__ bsum) {
    int idx = blockIdx.x * 256 + threadIdx.x;
    if (idx < WPK_US) {
        int e    = idx & 7;
        int lane = (idx >> 3) & 63;
        int q    = (idx >> 9) & 3;
        int gk   = idx >> 11;            // 0..255
        int kap  = gk & 15, g = gk >> 4;
        int k = kap * 32 + ((lane >> 4) << 3) + e;
        int j = q * 256 + g * 16 + (lane & 15);
        float wv = (k < 256) ? w_ih[j * 256 + k] : w_hh[j * 256 + (k - 256)];
        wpk[idx] = f2bf(wv);             // hi only
    }
    if (idx < WPKIN_US) {
        int e    = idx & 7;
        int lane = (idx >> 3) & 63;
        int d    = (idx >> 9) & 1;
        int tau  = idx >> 10;            // 0..15
        int k = ((lane >> 4) << 3) + e;
        int n = tau * 16 + (lane & 15);
        float wv = (k < NX + 1) ? w_in[n * (NX + 1) + k] : 0.0f;
        unsigned short hi = f2bf(wv);
        wpkin[idx] = d ? f2bf(wv - bf2f(hi)) : hi;
    }
    if (idx < 4 * H) bsum[idx] = b_ih[idx] + b_hh[idx];
}

// ---------------- main persistent LSTM ----------------
// R9 theory: per-CU L2 weight stream (~6.8 us/step for 1 MB) is the floor;
// 52/128 VGPRs used leaves 300 KB/CU of register file idle.
//  - persist kaps 8..10 in VGPRs (stream 1 MB -> 832 KB/step)
//  - prefetch kap 11 chunk across the step boundary (latency under E/P5/P1/X)
//  - 3 barriers/step instead of 4: G split into h-kaps (8..15, pre-barrier,
//    disjoint from X's writes to planes 0..7) and x-kaps (0..7, post-barrier)
//  - x/y for t+1 prefetched into regs during G part 2 (P1 becomes pure LDS)
__global__ __attribute__((amdgpu_flat_work_group_size(THREADS, THREADS),
                          amdgpu_waves_per_eu(4, 4)))
void lstm_main(const float* __restrict__ x,
               const float* __restrict__ y,
               const float* __restrict__ b_in,
               const float* __restrict__ w_out,
               const float* __restrict__ b_out,
               const unsigned short* __restrict__ wpk,
               const unsigned short* __restrict__ wpkin,
               const float* __restrict__ bsum,
               float* __restrict__ out) {
    // fragment-major activation buffers: [kap][lane*8+e], lane = qp*16 + m
    __shared__ __align__(16) unsigned short Agh[16][512];   // 16 KB
    __shared__ __align__(16) unsigned short Agl[16][512];   // 16 KB
    __shared__ __align__(16) unsigned short Xh[512];        // 1 KB
    __shared__ __align__(16) unsigned short Xl[512];        // 1 KB
    __shared__ float y_part[16][16];
    __shared__ float lds_pad[12288];    // total ~84 KB -> 1 block/CU

    const int tid  = threadIdx.x;
    const int w    = tid >> 6;          // wave 0..15; owns output group g = w
    const int lane = tid & 63;
    const int col  = lane & 15;
    const int quad = lane >> 4;
    const int g0   = blockIdx.x * CPB;

    // per-wave constants: lane owns hidden index jh = w*16 + col
    const int   jh   = w * 16 + col;
    const float b_i  = bsum[jh];
    const float b_f  = bsum[256 + jh];
    const float b_g  = bsum[512 + jh];
    const float b_o  = bsum[768 + jh];
    const float wo   = w_out[jh];
    const float bi_x = b_in[jh];
    const float bout = b_out[0];
    const int   kq_x = jh >> 5;                   // x0 write plane (0..7)
    const int   kq_h = 8 + (jh >> 5);             // h write plane (8..15)
    const int   qp_w = (jh >> 3) & 3;
    const int   e_w  = jh & 7;
    const unsigned short* bbase = wpk + (size_t)(w * 16) * 4 * 512 + lane * 8;
    const unsigned short* bx_hi = wpkin + (w * 2 + 0) * 512 + lane * 8;
    const unsigned short* bx_lo = wpkin + (w * 2 + 1) * 512 + lane * 8;

    if (bout == -1234567.25f) {     // keep lds_pad alive (never true)
        lds_pad[tid] = (float)tid;
        lds_pad[tid + 4096] = 1.f;
        lds_pad[tid + 8192] = 2.f;
    }

    // zero-init LDS (h planes must be 0 at t=0; pad cols stay 0 forever)
    {
        unsigned int* p;
        p = (unsigned int*)&Agh[0][0];
        for (int i = tid; i < 16 * 256; i += THREADS) p[i] = 0u;
        p = (unsigned int*)&Agl[0][0];
        for (int i = tid; i < 16 * 256; i += THREADS) p[i] = 0u;
        if (tid < 256) ((unsigned int*)&Xh[0])[tid] = 0u;
        if (tid < 256) ((unsigned int*)&Xl[0])[tid] = 0u;
    }

    // ---- prologue loads: persistent weight kaps, prefetch chunk, w_in frags,
    //      and x/y for t=0 (all overlap the LDS zero-init)
    v8s Bp[KPERS][4];
    #pragma unroll
    for (int kp = 0; kp < KPERS; ++kp) {
        #pragma unroll
        for (int c2 = 0; c2 < 4; ++c2)
            Bp[kp][c2] = *(const v8s*)(bbase + ((size_t)(8 + kp) * 4 + c2) * 512);
    }
    v8s Bpre[4];
    #pragma unroll
    for (int c2 = 0; c2 < 4; ++c2)
        Bpre[c2] = *(const v8s*)(bbase + ((size_t)KPRE * 4 + c2) * 512);

    const v8s bxh = *(const v8s*)bx_hi;     // per-wave constant across steps
    const v8s bxl = *(const v8s*)bx_lo;

    float xv = 0.0f, yv = 0.0f;
    if (tid < CPB * NX) xv = x[(size_t)g0 * NX + tid];
    if (tid < CPB)      yv = y[(size_t)g0 + tid];

    float c_st[4];
    #pragma unroll
    for (int r = 0; r < 4; ++r) c_st[r] = 0.0f;
    __syncthreads();

    for (int t = 0; t < NT; ++t) {
        // ---- P1': stage xcat from prefetched regs (pure LDS, no global loads)
        if (tid < CPB * NX) {
            float v  = xv;
            int cell = tid / NX;
            int k    = tid - cell * NX;
            int pos  = (((k >> 3) << 4) + cell) * 8 + (k & 7);
            unsigned short hi = f2bf(v);
            Xh[pos] = hi;
            Xl[pos] = f2bf(v - bf2f(hi));
        }
        if (tid < CPB) {
            if (!__builtin_isnan(yv)) {
                int pos = (2 * 16 + tid) * 8 + 4;     // k = 20
                unsigned short hi = f2bf(yv);
                Xh[pos] = hi;
                Xl[pos] = f2bf(yv - bf2f(hi));
            }
        }
        __syncthreads();                               // barrier A

        // ---- X: x0 = relu(xcat @ w_in^T + b_in); writes planes 0..7 only
        {
            v8s xah = *(const v8s*)&Xh[lane * 8];
            v8s xal = *(const v8s*)&Xl[lane * 8];
            v4f xacc = {0.0f, 0.0f, 0.0f, 0.0f};
            xacc = MFMA_BF16(xah, bxh, xacc, 0, 0, 0);
            xacc = MFMA_BF16(xah, bxl, xacc, 0, 0, 0);
            xacc = MFMA_BF16(xal, bxh, xacc, 0, 0, 0);
            #pragma unroll
            for (int r = 0; r < 4; ++r) {
                int cell = quad * 4 + r;
                if (cell < CPB) {
                    float v = fmaxf(xacc[r] + bi_x, 0.0f);
                    unsigned short hi = f2bf(v);
                    int pos = (qp_w * 16 + cell) * 8 + e_w;
                    Agh[kq_x][pos] = hi;
                    Agl[kq_x][pos] = f2bf(v - bf2f(hi));
                }
            }
        }
        // no barrier: G part 1 reads planes 8..15, disjoint from X's writes

        // ---- G part 1: h-kaps 8..15 (h_{t-1}, valid since barrier A)
        v4f acc[4];
        #pragma unroll
        for (int q = 0; q < 4; ++q) acc[q] = (v4f){0.0f, 0.0f, 0.0f, 0.0f};

        // persisted kaps 8..10: zero L2 traffic
        #pragma unroll
        for (int kp = 0; kp < KPERS; ++kp) {
            v8s Ah = *(const v8s*)&Agh[8 + kp][lane * 8];
            v8s Al = *(const v8s*)&Agl[8 + kp][lane * 8];
            #pragma unroll
            for (int q = 0; q < 4; ++q) {
                acc[q] = MFMA_BF16(Ah, Bp[kp][q], acc[q], 0, 0, 0);
                acc[q] = MFMA_BF16(Al, Bp[kp][q], acc[q], 0, 0, 0);
            }
        }
        // kap 11: loads were issued before last step's P5 -> already landed
        {
            v8s Ah = *(const v8s*)&Agh[KPRE][lane * 8];
            v8s Al = *(const v8s*)&Agl[KPRE][lane * 8];
            #pragma unroll
            for (int q = 0; q < 4; ++q) {
                acc[q] = MFMA_BF16(Ah, Bpre[q], acc[q], 0, 0, 0);
                acc[q] = MFMA_BF16(Al, Bpre[q], acc[q], 0, 0, 0);
            }
        }
        // streamed kaps 12..15
        #pragma unroll 1
        for (int kap = 12; kap < 16; ++kap) {
            const unsigned short* bp = bbase + (size_t)kap * 4 * 512;
            v8s B[4];
            #pragma unroll
            for (int c2 = 0; c2 < 4; ++c2)
                B[c2] = *(const v8s*)(bp + c2 * 512);
            v8s Ah = *(const v8s*)&Agh[kap][lane * 8];
            v8s Al = *(const v8s*)&Agl[kap][lane * 8];
            #pragma unroll
            for (int q = 0; q < 4; ++q) {
                acc[q] = MFMA_BF16(Ah, B[q], acc[q], 0, 0, 0);
                acc[q] = MFMA_BF16(Al, B[q], acc[q], 0, 0, 0);
            }
        }
        __syncthreads();                               // barrier B (orders X writes)

        // ---- prefetch x/y for t+1 (lands during G part 2; clamped at NT-1)
        {
            const int tn = (t + 1 < NT) ? (t + 1) : t;
            if (tid < CPB * NX)
                xv = x[((size_t)tn * NGRID + g0) * NX + tid];
            if (tid < CPB)
                yv = y[(size_t)tn * NGRID + g0 + tid];
        }

        // ---- G part 2: x-kaps 0..7 (x0 written by X, ordered by barrier B)
        #pragma unroll 1
        for (int kap = 0; kap < 8; ++kap) {
            const unsigned short* bp = bbase + (size_t)kap * 4 * 512;
            v8s B[4];
            #pragma unroll
            for (int c2 = 0; c2 < 4; ++c2)
                B[c2] = *(const v8s*)(bp + c2 * 512);
            v8s Ah = *(const v8s*)&Agh[kap][lane * 8];
            v8s Al = *(const v8s*)&Agl[kap][lane * 8];
            #pragma unroll
            for (int q = 0; q < 4; ++q) {
                acc[q] = MFMA_BF16(Ah, B[q], acc[q], 0, 0, 0);
                acc[q] = MFMA_BF16(Al, B[q], acc[q], 0, 0, 0);
            }
        }

        // ---- E: pointwise LSTM + h writeback + y partial
        // (no barrier needed: all h-plane reads finished before barrier B;
        //  E writes planes 8..15, other waves' G part 2 reads planes 0..7)
        {
            float yp[4];
            #pragma unroll
            for (int r = 0; r < 4; ++r) {
                int cell = quad * 4 + r;
                float iv = acc[0][r] + b_i;
                float fv = acc[1][r] + b_f;
                float gv = acc[2][r] + b_g;
                float ov = acc[3][r] + b_o;
                float c  = fmaf(sigm(fv), c_st[r], sigm(iv) * tanh_f(gv));
                c_st[r]  = c;
                float h  = sigm(ov) * tanh_f(c);
                yp[r] = 0.0f;
                if (cell < CPB) {
                    unsigned short hi = f2bf(h);
                    int pos = (qp_w * 16 + cell) * 8 + e_w;
                    Agh[kq_h][pos] = hi;
                    Agl[kq_h][pos] = f2bf(h - bf2f(hi));
                    yp[r] = h * wo;
                }
            }
            #pragma unroll
            for (int r = 0; r < 4; ++r) {
                float p = yp[r];
                p += __shfl_xor(p, 1);
                p += __shfl_xor(p, 2);
                p += __shfl_xor(p, 4);
                p += __shfl_xor(p, 8);
                if (col == 0)
                    y_part[w][quad * 4 + r] = p;
            }
        }
        __syncthreads();                               // barrier C

        // ---- re-issue Bpre for next step: its L2 latency hides under
        //      P5 + P1' + X of the next iteration
        #pragma unroll
        for (int c2 = 0; c2 < 4; ++c2)
            Bpre[c2] = *(const v8s*)(bbase + ((size_t)KPRE * 4 + c2) * 512);

        // ---- P5: finalize y, store, feed back into xcat k=20
        // (no loop-end barrier: next barrier A orders these writes vs the
        //  next X-phase reads; k=20 obs overwrite is same-thread)
        if (tid < CPB) {
            float yfin = bout;
            #pragma unroll
            for (int w2 = 0; w2 < 16; ++w2) yfin += y_part[w2][tid];
            out[(size_t)t * NGRID + g0 + tid] = yfin;
            int pos = (2 * 16 + tid) * 8 + 4;             // k = 20
            unsigned short hi = f2bf(yfin);
            Xh[pos] = hi;
            Xl[pos] = f2bf(yfin - bf2f(hi));
        }
    }

    // keep-alive read for lds_pad (never executes)
    if (bout == -1234567.25f)
        out[tid & 3] += lds_pad[tid] + lds_pad[tid + 4096] + lds_pad[tid + 8192];
}

extern "C" void kernel_launch(void* const* d_in, const int* in_sizes, int n_in,
                              void* d_out, int out_size, void* d_ws, size_t ws_size,
                              hipStream_t stream) {
    const float* x     = (const float*)d_in[0];
    const float* y     = (const float*)d_in[1];
    const float* w_in  = (const float*)d_in[2];
    const float* b_in  = (const float*)d_in[3];
    const float* w_ih  = (const float*)d_in[4];
    const float* b_ih  = (const float*)d_in[5];
    const float* w_hh  = (const float*)d_in[6];
    const float* b_hh  = (const float*)d_in[7];
    const float* w_out = (const float*)d_in[8];
    const float* b_out = (const float*)d_in[9];

    unsigned short* wpk   = (unsigned short*)d_ws;
    unsigned short* wpkin = wpk + WPK_US;
    float*          bsum  = (float*)(wpkin + WPKIN_US);
    float*          out   = (float*)d_out;

    prep_kernel<<<(WPK_US + 255) / 256, 256, 0, stream>>>(
        w_in, w_ih, w_hh, b_ih, b_hh, wpk, wpkin, bsum);
    lstm_main<<<NBLK, THREADS, 0, stream>>>(
        x, y, b_in, w_out, b_out, wpk, wpkin, bsum, out);
}

// Round 2
// 3967.974 us; speedup vs baseline: 1.2543x; 1.2543x over previous
//
#include <hip/hip_runtime.h>
#include <math.h>

#define NT     365
#define NGRID  3000
#define NX     20
#define H      256
#define CPB    15
#define NBLK   (NGRID/CPB)     // 200 blocks, 1 per CU
#define THREADS 1024           // 16 waves, 4 per SIMD

// packed weight sizes (ushorts)
// wpk HI-ONLY: [g 16][kap 16][q 4][lane 64][e 8]
#define WPK_US   (16*16*4*64*8)   // 524,288
#define WPKIN_US (16*2*64*8)      // 16,384

typedef short v8s __attribute__((ext_vector_type(8)));
typedef float v4f __attribute__((ext_vector_type(4)));
#define MFMA_BF16 __builtin_amdgcn_mfma_f32_16x16x32_bf16

__device__ __forceinline__ unsigned short f2bf(float f) {
    unsigned int u = __float_as_uint(f);
    u += 0x7fffu + ((u >> 16) & 1u);          // RTNE
    return (unsigned short)(u >> 16);
}
__device__ __forceinline__ float bf2f(unsigned short h) {
    return __uint_as_float(((unsigned int)h) << 16);
}
__device__ __forceinline__ float sigm(float x)  { return 1.0f / (1.0f + __expf(-x)); }
__device__ __forceinline__ float tanh_f(float x){ return 2.0f * sigm(2.0f * x) - 1.0f; }

// ---------------- weight pre-pack (unchanged) ----------------
__global__ void prep_kernel(const float* __restrict__ w_in,
                            const float* __restrict__ w_ih,
                            const float* __restrict__ w_hh,
                            const float* __restrict__ b_ih,
                            const float* __restrict__ b_hh,
                            unsigned short* __restrict__ wpk,
                            unsigned short* __restrict__ wpkin,
                            float* __restrict__ bsum) {
    int idx = blockIdx.x * 256 + threadIdx.x;
    if (idx < WPK_US) {
        int e    = idx & 7;
        int lane = (idx >> 3) & 63;
        int q    = (idx >> 9) & 3;
        int gk   = idx >> 11;            // 0..255
        int kap  = gk & 15, g = gk >> 4;
        int k = kap * 32 + ((lane >> 4) << 3) + e;
        int j = q * 256 + g * 16 + (lane & 15);
        float wv = (k < 256) ? w_ih[j * 256 + k] : w_hh[j * 256 + (k - 256)];
        wpk[idx] = f2bf(wv);             // hi only
    }
    if (idx < WPKIN_US) {
        int e    = idx & 7;
        int lane = (idx >> 3) & 63;
        int d    = (idx >> 9) & 1;
        int tau  = idx >> 10;            // 0..15
        int k = ((lane >> 4) << 3) + e;
        int n = tau * 16 + (lane & 15);
        float wv = (k < NX + 1) ? w_in[n * (NX + 1) + k] : 0.0f;
        unsigned short hi = f2bf(wv);
        wpkin[idx] = d ? f2bf(wv - bf2f(hi)) : hi;
    }
    if (idx < 4 * H) bsum[idx] = b_ih[idx] + b_hh[idx];
}

// ---------------- main persistent LSTM ----------------
// R10: fix R9's scratch-spill of "persistent" weights.
//  - R9 evidence: FETCH 57MB->1.5GB, VGPR only 64 -> Bp[][]/Bpre[] arrays
//    went to scratch (failed SROA), thrashing per-XCD L2 from scratch reads.
//  - Fix A: NAMED v8s locals (B8_0..B10_3, 48 VGPRs) for kaps 8..10 --
//    static uses only, trivially register-promotable. Target VGPR ~110 < 128.
//  - Fix B: kap 11 persisted in LDS (Bw11, 4 KB/wave = 64 KB) replacing the
//    dead lds_pad; LDS ~99 KB keeps 1 block/CU. Zero L2 traffic for kap 11.
//  - Weight stream/step: 1 MB -> 768 KB (-25%).
//  - Keep R9's validated 3-barrier schedule + x/y register prefetch.
__global__ __attribute__((amdgpu_flat_work_group_size(THREADS, THREADS),
                          amdgpu_waves_per_eu(4, 4)))
void lstm_main(const float* __restrict__ x,
               const float* __restrict__ y,
               const float* __restrict__ b_in,
               const float* __restrict__ w_out,
               const float* __restrict__ b_out,
               const unsigned short* __restrict__ wpk,
               const unsigned short* __restrict__ wpkin,
               const float* __restrict__ bsum,
               float* __restrict__ out) {
    // fragment-major activation buffers: [kap][lane*8+e], lane = qp*16 + m
    __shared__ __align__(16) unsigned short Agh[16][512];   // 16 KB
    __shared__ __align__(16) unsigned short Agl[16][512];   // 16 KB
    __shared__ __align__(16) unsigned short Xh[512];        // 1 KB
    __shared__ __align__(16) unsigned short Xl[512];        // 1 KB
    __shared__ __align__(16) unsigned short Bw11[16][2048]; // 64 KB kap-11 store
    __shared__ float y_part[16][16];
    // total ~99 KB -> 1 block/CU (2x99 > 160 KB)

    const int tid  = threadIdx.x;
    const int w    = tid >> 6;          // wave 0..15; owns output group g = w
    const int lane = tid & 63;
    const int col  = lane & 15;
    const int quad = lane >> 4;
    const int g0   = blockIdx.x * CPB;

    // per-wave constants: lane owns hidden index jh = w*16 + col
    const int   jh   = w * 16 + col;
    const float b_i  = bsum[jh];
    const float b_f  = bsum[256 + jh];
    const float b_g  = bsum[512 + jh];
    const float b_o  = bsum[768 + jh];
    const float wo   = w_out[jh];
    const float bi_x = b_in[jh];
    const float bout = b_out[0];
    const int   kq_x = jh >> 5;                   // x0 write plane (0..7)
    const int   kq_h = 8 + (jh >> 5);             // h write plane (8..15)
    const int   qp_w = (jh >> 3) & 3;
    const int   e_w  = jh & 7;
    const unsigned short* bbase = wpk + (size_t)(w * 16) * 4 * 512 + lane * 8;
    const unsigned short* bx_hi = wpkin + (w * 2 + 0) * 512 + lane * 8;
    const unsigned short* bx_lo = wpkin + (w * 2 + 1) * 512 + lane * 8;

    // zero-init LDS (h planes must be 0 at t=0; pad cols stay 0 forever)
    {
        unsigned int* p;
        p = (unsigned int*)&Agh[0][0];
        for (int i = tid; i < 16 * 256; i += THREADS) p[i] = 0u;
        p = (unsigned int*)&Agl[0][0];
        for (int i = tid; i < 16 * 256; i += THREADS) p[i] = 0u;
        if (tid < 256) ((unsigned int*)&Xh[0])[tid] = 0u;
        if (tid < 256) ((unsigned int*)&Xl[0])[tid] = 0u;
    }

    // ---- prologue: persistent weights (named regs + LDS), w_in frags,
    //      x/y for t=0 (all overlap the LDS zero-init)
#define LOADK(kap, c) (*(const v8s*)(bbase + ((size_t)(kap) * 4 + (c)) * 512))
    v8s B8_0  = LOADK(8, 0),  B8_1  = LOADK(8, 1),
        B8_2  = LOADK(8, 2),  B8_3  = LOADK(8, 3);
    v8s B9_0  = LOADK(9, 0),  B9_1  = LOADK(9, 1),
        B9_2  = LOADK(9, 2),  B9_3  = LOADK(9, 3);
    v8s B10_0 = LOADK(10, 0), B10_1 = LOADK(10, 1),
        B10_2 = LOADK(10, 2), B10_3 = LOADK(10, 3);

    // kap 11 -> LDS (per-wave 4 KB chunk, disjoint 16B writes per lane)
    {
        *(v8s*)&Bw11[w][0 * 512 + lane * 8] = LOADK(11, 0);
        *(v8s*)&Bw11[w][1 * 512 + lane * 8] = LOADK(11, 1);
        *(v8s*)&Bw11[w][2 * 512 + lane * 8] = LOADK(11, 2);
        *(v8s*)&Bw11[w][3 * 512 + lane * 8] = LOADK(11, 3);
    }

    const v8s bxh = *(const v8s*)bx_hi;     // per-wave constant across steps
    const v8s bxl = *(const v8s*)bx_lo;

    float xv = 0.0f, yv = 0.0f;
    if (tid < CPB * NX) xv = x[(size_t)g0 * NX + tid];
    if (tid < CPB)      yv = y[(size_t)g0 + tid];

    float c_st[4];
    #pragma unroll
    for (int r = 0; r < 4; ++r) c_st[r] = 0.0f;
    __syncthreads();

    // per-kap MFMA macro: named acc + named B regs, all-static uses
#define GEMM_KAP(KAP, B0, B1, B2, B3)                                   \
    {                                                                   \
        v8s Ah = *(const v8s*)&Agh[KAP][lane * 8];                      \
        v8s Al = *(const v8s*)&Agl[KAP][lane * 8];                      \
        acc0 = MFMA_BF16(Ah, B0, acc0, 0, 0, 0);                        \
        acc0 = MFMA_BF16(Al, B0, acc0, 0, 0, 0);                        \
        acc1 = MFMA_BF16(Ah, B1, acc1, 0, 0, 0);                        \
        acc1 = MFMA_BF16(Al, B1, acc1, 0, 0, 0);                        \
        acc2 = MFMA_BF16(Ah, B2, acc2, 0, 0, 0);                        \
        acc2 = MFMA_BF16(Al, B2, acc2, 0, 0, 0);                        \
        acc3 = MFMA_BF16(Ah, B3, acc3, 0, 0, 0);                        \
        acc3 = MFMA_BF16(Al, B3, acc3, 0, 0, 0);                        \
    }

    for (int t = 0; t < NT; ++t) {
        // ---- P1': stage xcat from prefetched regs (pure LDS, no global loads)
        if (tid < CPB * NX) {
            float v  = xv;
            int cell = tid / NX;
            int k    = tid - cell * NX;
            int pos  = (((k >> 3) << 4) + cell) * 8 + (k & 7);
            unsigned short hi = f2bf(v);
            Xh[pos] = hi;
            Xl[pos] = f2bf(v - bf2f(hi));
        }
        if (tid < CPB) {
            if (!__builtin_isnan(yv)) {
                int pos = (2 * 16 + tid) * 8 + 4;     // k = 20
                unsigned short hi = f2bf(yv);
                Xh[pos] = hi;
                Xl[pos] = f2bf(yv - bf2f(hi));
            }
        }
        __syncthreads();                               // barrier A

        // ---- X: x0 = relu(xcat @ w_in^T + b_in); writes planes 0..7 only
        {
            v8s xah = *(const v8s*)&Xh[lane * 8];
            v8s xal = *(const v8s*)&Xl[lane * 8];
            v4f xacc = {0.0f, 0.0f, 0.0f, 0.0f};
            xacc = MFMA_BF16(xah, bxh, xacc, 0, 0, 0);
            xacc = MFMA_BF16(xah, bxl, xacc, 0, 0, 0);
            xacc = MFMA_BF16(xal, bxh, xacc, 0, 0, 0);
            #pragma unroll
            for (int r = 0; r < 4; ++r) {
                int cell = quad * 4 + r;
                if (cell < CPB) {
                    float v = fmaxf(xacc[r] + bi_x, 0.0f);
                    unsigned short hi = f2bf(v);
                    int pos = (qp_w * 16 + cell) * 8 + e_w;
                    Agh[kq_x][pos] = hi;
                    Agl[kq_x][pos] = f2bf(v - bf2f(hi));
                }
            }
        }
        // no barrier: G part 1 reads planes 8..15, disjoint from X's writes

        // ---- G part 1: h-kaps 8..15 (h_{t-1}, valid since barrier A)
        v4f acc0 = {0.0f, 0.0f, 0.0f, 0.0f};
        v4f acc1 = {0.0f, 0.0f, 0.0f, 0.0f};
        v4f acc2 = {0.0f, 0.0f, 0.0f, 0.0f};
        v4f acc3 = {0.0f, 0.0f, 0.0f, 0.0f};

        // persisted kaps 8..10: zero memory traffic
        GEMM_KAP(8,  B8_0,  B8_1,  B8_2,  B8_3);
        GEMM_KAP(9,  B9_0,  B9_1,  B9_2,  B9_3);
        GEMM_KAP(10, B10_0, B10_1, B10_2, B10_3);

        // kap 11 from LDS: zero L2 traffic
        {
            v8s Bl0 = *(const v8s*)&Bw11[w][0 * 512 + lane * 8];
            v8s Bl1 = *(const v8s*)&Bw11[w][1 * 512 + lane * 8];
            v8s Bl2 = *(const v8s*)&Bw11[w][2 * 512 + lane * 8];
            v8s Bl3 = *(const v8s*)&Bw11[w][3 * 512 + lane * 8];
            v8s Ah  = *(const v8s*)&Agh[11][lane * 8];
            v8s Al  = *(const v8s*)&Agl[11][lane * 8];
            acc0 = MFMA_BF16(Ah, Bl0, acc0, 0, 0, 0);
            acc0 = MFMA_BF16(Al, Bl0, acc0, 0, 0, 0);
            acc1 = MFMA_BF16(Ah, Bl1, acc1, 0, 0, 0);
            acc1 = MFMA_BF16(Al, Bl1, acc1, 0, 0, 0);
            acc2 = MFMA_BF16(Ah, Bl2, acc2, 0, 0, 0);
            acc2 = MFMA_BF16(Al, Bl2, acc2, 0, 0, 0);
            acc3 = MFMA_BF16(Ah, Bl3, acc3, 0, 0, 0);
            acc3 = MFMA_BF16(Al, Bl3, acc3, 0, 0, 0);
        }

        // streamed kaps 12..15
        #pragma unroll 1
        for (int kap = 12; kap < 16; ++kap) {
            const unsigned short* bp = bbase + (size_t)kap * 4 * 512;
            v8s Bs0 = *(const v8s*)(bp + 0 * 512);
            v8s Bs1 = *(const v8s*)(bp + 1 * 512);
            v8s Bs2 = *(const v8s*)(bp + 2 * 512);
            v8s Bs3 = *(const v8s*)(bp + 3 * 512);
            v8s Ah  = *(const v8s*)&Agh[kap][lane * 8];
            v8s Al  = *(const v8s*)&Agl[kap][lane * 8];
            acc0 = MFMA_BF16(Ah, Bs0, acc0, 0, 0, 0);
            acc0 = MFMA_BF16(Al, Bs0, acc0, 0, 0, 0);
            acc1 = MFMA_BF16(Ah, Bs1, acc1, 0, 0, 0);
            acc1 = MFMA_BF16(Al, Bs1, acc1, 0, 0, 0);
            acc2 = MFMA_BF16(Ah, Bs2, acc2, 0, 0, 0);
            acc2 = MFMA_BF16(Al, Bs2, acc2, 0, 0, 0);
            acc3 = MFMA_BF16(Ah, Bs3, acc3, 0, 0, 0);
            acc3 = MFMA_BF16(Al, Bs3, acc3, 0, 0, 0);
        }
        __syncthreads();                               // barrier B (orders X writes)

        // ---- prefetch x/y for t+1 (lands during G part 2; clamped at NT-1)
        {
            const int tn = (t + 1 < NT) ? (t + 1) : t;
            if (tid < CPB * NX)
                xv = x[((size_t)tn * NGRID + g0) * NX + tid];
            if (tid < CPB)
                yv = y[(size_t)tn * NGRID + g0 + tid];
        }

        // ---- G part 2: x-kaps 0..7 (x0 written by X, ordered by barrier B)
        #pragma unroll 1
        for (int kap = 0; kap < 8; ++kap) {
            const unsigned short* bp = bbase + (size_t)kap * 4 * 512;
            v8s Bs0 = *(const v8s*)(bp + 0 * 512);
            v8s Bs1 = *(const v8s*)(bp + 1 * 512);
            v8s Bs2 = *(const v8s*)(bp + 2 * 512);
            v8s Bs3 = *(const v8s*)(bp + 3 * 512);
            v8s Ah  = *(const v8s*)&Agh[kap][lane * 8];
            v8s Al  = *(const v8s*)&Agl[kap][lane * 8];
            acc0 = MFMA_BF16(Ah, Bs0, acc0, 0, 0, 0);
            acc0 = MFMA_BF16(Al, Bs0, acc0, 0, 0, 0);
            acc1 = MFMA_BF16(Ah, Bs1, acc1, 0, 0, 0);
            acc1 = MFMA_BF16(Al, Bs1, acc1, 0, 0, 0);
            acc2 = MFMA_BF16(Ah, Bs2, acc2, 0, 0, 0);
            acc2 = MFMA_BF16(Al, Bs2, acc2, 0, 0, 0);
            acc3 = MFMA_BF16(Ah, Bs3, acc3, 0, 0, 0);
            acc3 = MFMA_BF16(Al, Bs3, acc3, 0, 0, 0);
        }

        // ---- E: pointwise LSTM + h writeback + y partial
        // (no barrier needed: all h-plane reads finished before barrier B;
        //  E writes planes 8..15, other waves' G part 2 reads planes 0..7)
        {
            float yp[4];
            #pragma unroll
            for (int r = 0; r < 4; ++r) {
                int cell = quad * 4 + r;
                float iv = acc0[r] + b_i;
                float fv = acc1[r] + b_f;
                float gv = acc2[r] + b_g;
                float ov = acc3[r] + b_o;
                float c  = fmaf(sigm(fv), c_st[r], sigm(iv) * tanh_f(gv));
                c_st[r]  = c;
                float h  = sigm(ov) * tanh_f(c);
                yp[r] = 0.0f;
                if (cell < CPB) {
                    unsigned short hi = f2bf(h);
                    int pos = (qp_w * 16 + cell) * 8 + e_w;
                    Agh[kq_h][pos] = hi;
                    Agl[kq_h][pos] = f2bf(h - bf2f(hi));
                    yp[r] = h * wo;
                }
            }
            #pragma unroll
            for (int r = 0; r < 4; ++r) {
                float p = yp[r];
                p += __shfl_xor(p, 1);
                p += __shfl_xor(p, 2);
                p += __shfl_xor(p, 4);
                p += __shfl_xor(p, 8);
                if (col == 0)
                    y_part[w][quad * 4 + r] = p;
            }
        }
        __syncthreads();                               // barrier C

        // ---- P5: finalize y, store, feed back into xcat k=20
        // (no loop-end barrier: next barrier A orders these writes vs the
        //  next X-phase reads; k=20 obs overwrite is same-thread)
        if (tid < CPB) {
            float yfin = bout;
            #pragma unroll
            for (int w2 = 0; w2 < 16; ++w2) yfin += y_part[w2][tid];
            out[(size_t)t * NGRID + g0 + tid] = yfin;
            int pos = (2 * 16 + tid) * 8 + 4;             // k = 20
            unsigned short hi = f2bf(yfin);
            Xh[pos] = hi;
            Xl[pos] = f2bf(yfin - bf2f(hi));
        }
    }
}

extern "C" void kernel_launch(void* const* d_in, const int* in_sizes, int n_in,
                              void* d_out, int out_size, void* d_ws, size_t ws_size,
                              hipStream_t stream) {
    const float* x     = (const float*)d_in[0];
    const float* y     = (const float*)d_in[1];
    const float* w_in  = (const float*)d_in[2];
    const float* b_in  = (const float*)d_in[3];
    const float* w_ih  = (const float*)d_in[4];
    const float* b_ih  = (const float*)d_in[5];
    const float* w_hh  = (const float*)d_in[6];
    const float* b_hh  = (const float*)d_in[7];
    const float* w_out = (const float*)d_in[8];
    const float* b_out = (const float*)d_in[9];

    unsigned short* wpk   = (unsigned short*)d_ws;
    unsigned short* wpkin = wpk + WPK_US;
    float*          bsum  = (float*)(wpkin + WPKIN_US);
    float*          out   = (float*)d_out;

    prep_kernel<<<(WPK_US + 255) / 256, 256, 0, stream>>>(
        w_in, w_ih, w_hh, b_ih, b_hh, wpk, wpkin, bsum);
    lstm_main<<<NBLK, THREADS, 0, stream>>>(
        x, y, b_in, w_out, b_out, wpk, wpkin, bsum, out);
}